// Round 14
// baseline (207.046 us; speedup 1.0000x reference)
//
#include <hip/hip_runtime.h>
#include <hip/hip_bf16.h>

typedef unsigned short u16;
typedef __attribute__((ext_vector_type(4))) float  f32x4;
typedef __attribute__((ext_vector_type(8))) short  s16x8;
typedef __attribute__((ext_vector_type(4))) int    i32x4;

#define MFMA32(a,b,c) __builtin_amdgcn_mfma_f32_16x16x32_bf16((a),(b),(c),0,0,0)

__device__ __forceinline__ short f2bf(float f) {
  unsigned u = __float_as_uint(f);
  u = (u + 0x7fffu + ((u >> 16) & 1u)) >> 16;
  return (short)u;
}
__device__ __forceinline__ unsigned packbf(float lo, float hi) {
  return (unsigned)(u16)f2bf(lo) | ((unsigned)(u16)f2bf(hi) << 16);
}
__device__ __forceinline__ unsigned cvtpk(float a, float b) {
  float2 f; f.x = a; f.y = b;
  __hip_bfloat162 h = __float22bfloat162_rn(f);
  unsigned u; __builtin_memcpy(&u, &h, 4); return u;
}

// Geometry: B=16,T=4096,C=256 -> 256 windows of W=256, H=4, DH=64, RADIUS=32

// ---------------- K0: weight cast + transpose ----------------
__global__ __launch_bounds__(256) void k_prep(const float* __restrict__ wqkv,
                                              const float* __restrict__ wproj,
                                              u16* __restrict__ wqkvT,
                                              u16* __restrict__ wprojT) {
  int idx = blockIdx.x * 256 + threadIdx.x;
  if (idx < 768 * 256) {
    int n = idx >> 8, kk = idx & 255;
    wqkvT[idx] = (u16)f2bf(wqkv[kk * 768 + n]);
  } else {
    int j = idx - 768 * 256;
    int n = j >> 8, kk = j & 255;
    wprojT[j] = (u16)f2bf(wproj[kk * 256 + n]);
  }
}

// ---------------- K1: fully fused per-window QKV + banded attention + projection ----
// 1 block = 1 window (256 rows). 8 waves; wave w owns output rows 32w..32w+31.
// LDS bytes: K [j256][d64] @0 (32KB) | V^T [d64][j256] @32768 | Q [q256][d64] @65536
//            | Otmp per-wave 32x64 @98304 + w*4096.  All XOR-swizzled ^((row&7)<<4).
__global__ __launch_bounds__(512) void k_fused(const float* __restrict__ x,
                                               const u16* __restrict__ wqkvT,
                                               const u16* __restrict__ wprojT,
                                               const float* __restrict__ bias,
                                               float* __restrict__ out) {
  __shared__ u16 lds[65536];           // 128 KiB
  char* ldsb = (char*)lds;
  const int tid = threadIdx.x;
  const int lane = tid & 63, w = tid >> 6;
  const int c15 = lane & 15, g = lane >> 4;
  const int win = blockIdx.x;
  const unsigned swzq = ((unsigned)(c15 & 7)) << 4;   // swizzle for rows ≡ c15 (mod 8)

  // ---- x rows -> A-fragments in registers (reused 12x: Q,K GEMMs as A; V^T as B) ----
  s16x8 xa[2][8];
#pragma unroll
  for (int mt = 0; mt < 2; ++mt) {
    const float* xp = x + ((size_t)win * 256 + w * 32 + mt * 16 + c15) * 256;
#pragma unroll
    for (int kc = 0; kc < 8; ++kc) {
      f32x4 a = *(const f32x4*)(xp + kc * 32 + g * 8);
      f32x4 b = *(const f32x4*)(xp + kc * 32 + g * 8 + 4);
      i32x4 t = { (int)cvtpk(a[0], a[1]), (int)cvtpk(a[2], a[3]),
                  (int)cvtpk(b[0], b[1]), (int)cvtpk(b[2], b[3]) };
      xa[mt][kc] = *(s16x8*)&t;
    }
  }

  s16x8 of[2][8];    // O as projection A-frags (head h fills kc = 2h, 2h+1)

#pragma unroll
  for (int h = 0; h < 4; ++h) {
    // ---- GEMM Q (which=0 -> LDS @65536) and K (which=1 -> LDS @0) ----
#pragma unroll
    for (int wq = 0; wq < 2; ++wq) {
      const u16* wb = wqkvT + (size_t)(wq * 256 + h * 64) * 256;
      f32x4 acc[2][4] = {};
#pragma unroll
      for (int kc = 0; kc < 8; ++kc) {
        s16x8 bf[4];
#pragma unroll
        for (int nt = 0; nt < 4; ++nt)
          bf[nt] = *(const s16x8*)(wb + (size_t)(nt * 16 + c15) * 256 + kc * 32 + g * 8);
#pragma unroll
        for (int mt = 0; mt < 2; ++mt)
#pragma unroll
          for (int nt = 0; nt < 4; ++nt)
            acc[mt][nt] = MFMA32(xa[mt][kc], bf[nt], acc[mt][nt]);
      }
      char* dst = ldsb + (wq ? 0 : 65536);
#pragma unroll
      for (int mt = 0; mt < 2; ++mt)
#pragma unroll
        for (int nt = 0; nt < 4; ++nt)
#pragma unroll
          for (int r = 0; r < 4; ++r) {
            int row = w * 32 + mt * 16 + g * 4 + r;
            unsigned b = (unsigned)(row * 128 + (nt * 16 + c15) * 2) ^ (((unsigned)(row & 7)) << 4);
            *(u16*)(dst + b) = (u16)f2bf(acc[mt][nt][r]);
          }
    }
    // ---- GEMM V^T (which=2): A = W_V rows (d), B = xa (x as B-frag) -> LDS @32768 ----
    {
      const u16* wv = wqkvT + (size_t)(512 + h * 64) * 256;
      f32x4 acc[4][2] = {};
#pragma unroll
      for (int kc = 0; kc < 8; ++kc) {
        s16x8 af[4];
#pragma unroll
        for (int mtv = 0; mtv < 4; ++mtv)
          af[mtv] = *(const s16x8*)(wv + (size_t)(mtv * 16 + c15) * 256 + kc * 32 + g * 8);
#pragma unroll
        for (int mtv = 0; mtv < 4; ++mtv)
#pragma unroll
          for (int ntx = 0; ntx < 2; ++ntx)
            acc[mtv][ntx] = MFMA32(af[mtv], xa[ntx][kc], acc[mtv][ntx]);
      }
#pragma unroll
      for (int mtv = 0; mtv < 4; ++mtv)
#pragma unroll
        for (int ntx = 0; ntx < 2; ++ntx)
#pragma unroll
          for (int r = 0; r < 4; ++r) {
            int d = mtv * 16 + g * 4 + r;
            int j = w * 32 + ntx * 16 + c15;
            unsigned b = (unsigned)(d * 512 + j * 2) ^ (((unsigned)(d & 7)) << 4);
            *(u16*)(ldsb + 32768 + b) = (u16)f2bf(acc[mtv][ntx][r]);
          }
    }
    __syncthreads();   // K/V^T/Q published

    // ---- banded attention for this head, 2 q-tiles per wave ----
#pragma unroll
    for (int ii = 0; ii < 2; ++ii) {
      const int i16 = w * 2 + ii;
      const int qrow = i16 * 16 + c15;
      // Q B-frags (rows = own rows, via LDS transpose)
      const s16x8 qf0 = *(const s16x8*)(ldsb + 65536 + ((unsigned)(qrow * 128 + g * 16) ^ swzq));
      const s16x8 qf1 = *(const s16x8*)(ldsb + 65536 + ((unsigned)(qrow * 128 + 64 + g * 16) ^ swzq));
      // K A-frags for j-tiles i16, i16-1, i16-2
      s16x8 kl0, kh0, kl1 = {}, kh1 = {}, kl2 = {}, kh2 = {};
      {
        int row = i16 * 16 + c15;
        kl0 = *(const s16x8*)(ldsb + ((unsigned)(row * 128 + g * 16) ^ swzq));
        kh0 = *(const s16x8*)(ldsb + ((unsigned)(row * 128 + 64 + g * 16) ^ swzq));
      }
      if (i16 >= 1) {
        int row = (i16 - 1) * 16 + c15;
        kl1 = *(const s16x8*)(ldsb + ((unsigned)(row * 128 + g * 16) ^ swzq));
        kh1 = *(const s16x8*)(ldsb + ((unsigned)(row * 128 + 64 + g * 16) ^ swzq));
      }
      if (i16 >= 2) {
        int row = (i16 - 2) * 16 + c15;
        kl2 = *(const s16x8*)(ldsb + ((unsigned)(row * 128 + g * 16) ^ swzq));
        kh2 = *(const s16x8*)(ldsb + ((unsigned)(row * 128 + 64 + g * 16) ^ swzq));
      }

      f32x4 sT0 = {}, sT1 = {}, sT2 = {};
      sT0 = MFMA32(kl0, qf0, sT0); sT0 = MFMA32(kh0, qf1, sT0);
      if (i16 >= 1) { sT1 = MFMA32(kl1, qf0, sT1); sT1 = MFMA32(kh1, qf1, sT1); }
      if (i16 >= 2) { sT2 = MFMA32(kl2, qf0, sT2); sT2 = MFMA32(kh2, qf1, sT2); }

      float e0[4], e1[4], e2[4];
      float vmax = -3.0e38f;
#pragma unroll
      for (int r = 0; r < 4; ++r) {
        int dd = qrow - (i16 * 16 + g * 4 + r);
        e0[r] = (dd >= 0 && dd <= 32) ? sT0[r] * 0.125f : -1.0e30f;
        vmax = fmaxf(vmax, e0[r]);
      }
      if (i16 >= 1) {
#pragma unroll
        for (int r = 0; r < 4; ++r) {          // dd in 1..31, always in band
          e1[r] = sT1[r] * 0.125f;
          vmax = fmaxf(vmax, e1[r]);
        }
      }
      if (i16 >= 2) {
#pragma unroll
        for (int r = 0; r < 4; ++r) {
          int dd = qrow - ((i16 - 2) * 16 + g * 4 + r);   // 17..47
          e2[r] = (dd <= 32) ? sT2[r] * 0.125f : -1.0e30f;
          vmax = fmaxf(vmax, e2[r]);
        }
      }
      vmax = fmaxf(vmax, __shfl_xor(vmax, 16));
      vmax = fmaxf(vmax, __shfl_xor(vmax, 32));
      float ssum = 0.0f;
#pragma unroll
      for (int r = 0; r < 4; ++r) { e0[r] = __expf(e0[r] - vmax); ssum += e0[r]; }
      if (i16 >= 1) {
#pragma unroll
        for (int r = 0; r < 4; ++r) { e1[r] = __expf(e1[r] - vmax); ssum += e1[r]; }
      }
      if (i16 >= 2) {
#pragma unroll
        for (int r = 0; r < 4; ++r) { e2[r] = __expf(e2[r] - vmax); ssum += e2[r]; }
      }
      ssum += __shfl_xor(ssum, 16);
      ssum += __shfl_xor(ssum, 32);
      const float inv = 1.0f / ssum;

      unsigned c0a = packbf(e0[0] * inv, e0[1] * inv), c0b = packbf(e0[2] * inv, e0[3] * inv);
      unsigned c1a = 0, c1b = 0, c2a = 0, c2b = 0;
      if (i16 >= 1) { c1a = packbf(e1[0] * inv, e1[1] * inv); c1b = packbf(e1[2] * inv, e1[3] * inv); }
      if (i16 >= 2) { c2a = packbf(e2[0] * inv, e2[1] * inv); c2b = packbf(e2[2] * inv, e2[3] * inv); }

      const int src0 = ((g & 1) << 5) + c15;
      const int src1 = src0 + 16;
      const bool alo = (g < 2);
#define MKFRAG(pa, ua, ub) do {                                             \
        int _t0 = __shfl((int)(ua), src0), _t1 = __shfl((int)(ub), src0);   \
        int _t2 = __shfl((int)(ua), src1), _t3 = __shfl((int)(ub), src1);   \
        i32x4 _ti = { alo ? _t0 : 0, alo ? _t1 : 0, alo ? _t2 : 0, alo ? _t3 : 0 }; \
        pa = *(s16x8*)&_ti;                                                 \
      } while (0)
      s16x8 pa0, pa1, pa2;
      MKFRAG(pa0, c0a, c0b);
      MKFRAG(pa1, c1a, c1b);
      MKFRAG(pa2, c2a, c2b);
#undef MKFRAG

      f32x4 oa[4] = {};
#pragma unroll
      for (int dt = 0; dt < 4; ++dt) {
        int d = dt * 16 + c15;
        s16x8 v0 = *(const s16x8*)(ldsb + 32768 +
                    ((unsigned)(d * 512 + (i16 * 16 + (g & 1) * 8) * 2) ^ swzq));
        oa[dt] = MFMA32(pa0, v0, oa[dt]);
        if (i16 >= 1) {
          s16x8 v1 = *(const s16x8*)(ldsb + 32768 +
                      ((unsigned)(d * 512 + ((i16 - 1) * 16 + (g & 1) * 8) * 2) ^ swzq));
          oa[dt] = MFMA32(pa1, v1, oa[dt]);
        }
        if (i16 >= 2) {
          s16x8 v2 = *(const s16x8*)(ldsb + 32768 +
                      ((unsigned)(d * 512 + ((i16 - 2) * 16 + (g & 1) * 8) * 2) ^ swzq));
          oa[dt] = MFMA32(pa2, v2, oa[dt]);
        }
      }
      // O tile -> per-wave Otmp
#pragma unroll
      for (int dt = 0; dt < 4; ++dt)
#pragma unroll
        for (int r = 0; r < 4; ++r) {
          int lrow = ii * 16 + g * 4 + r;
          unsigned b = (unsigned)(lrow * 128 + (dt * 16 + c15) * 2) ^ (((unsigned)(lrow & 7)) << 4);
          *(u16*)(ldsb + 98304 + w * 4096 + b) = (u16)f2bf(oa[dt][r]);
        }
    } // ii

    // ---- O readback as projection A-frags (own-wave region; cols h*64..h*64+63) ----
#pragma unroll
    for (int mt = 0; mt < 2; ++mt)
#pragma unroll
      for (int kh = 0; kh < 2; ++kh) {
        unsigned b = (unsigned)((mt * 16 + c15) * 128 + kh * 64 + g * 16) ^ swzq;
        of[mt][h * 2 + kh] = *(const s16x8*)(ldsb + 98304 + w * 4096 + b);
      }
    __syncthreads();   // protect K/V/Q LDS reuse by next head
  } // h

  // ---- projection: out = O @ Wproj + bias (per wave: 32 rows x 256 cols) ----
  const int obase = win * 256 + w * 32;
  for (int nt = 0; nt < 16; ++nt) {
    s16x8 bp[8];
#pragma unroll
    for (int kc = 0; kc < 8; ++kc)
      bp[kc] = *(const s16x8*)(wprojT + (size_t)(nt * 16 + c15) * 256 + kc * 32 + g * 8);
    const float bv = bias[nt * 16 + c15];
    f32x4 a0 = {bv, bv, bv, bv};
    f32x4 a1 = {bv, bv, bv, bv};
#pragma unroll
    for (int kc = 0; kc < 8; ++kc) {
      a0 = MFMA32(of[0][kc], bp[kc], a0);
      a1 = MFMA32(of[1][kc], bp[kc], a1);
    }
#pragma unroll
    for (int r = 0; r < 4; ++r) {
      out[(size_t)(obase + g * 4 + r) * 256 + nt * 16 + c15] = a0[r];
      out[(size_t)(obase + 16 + g * 4 + r) * 256 + nt * 16 + c15] = a1[r];
    }
  }
}

extern "C" void kernel_launch(void* const* d_in, const int* in_sizes, int n_in,
                              void* d_out, int out_size, void* d_ws, size_t ws_size,
                              hipStream_t stream) {
  (void)in_sizes; (void)n_in; (void)out_size;
  const float* x     = (const float*)d_in[0];
  const float* wqkv  = (const float*)d_in[1];
  const float* wproj = (const float*)d_in[2];
  const float* bias  = (const float*)d_in[3];
  float* out = (float*)d_out;
  char* ws = (char*)d_ws;

  const size_t wBytes = (size_t)768 * 256 * 2 + (size_t)256 * 256 * 2;  // 524288
  if (ws_size < wBytes) return;
  u16* wqkvT  = (u16*)ws;
  u16* wprojT = (u16*)(ws + (size_t)768 * 256 * 2);

  k_prep<<<1024, 256, 0, stream>>>(wqkv, wproj, wqkvT, wprojT);
  k_fused<<<256, 512, 0, stream>>>(x, wqkvT, wprojT, bias, out);
}

// Round 15
// 207.043 us; speedup vs baseline: 1.0000x; 1.0000x over previous
//
#include <hip/hip_runtime.h>
#include <hip/hip_bf16.h>

typedef unsigned short u16;
typedef __attribute__((ext_vector_type(4))) float  f32x4;
typedef __attribute__((ext_vector_type(8))) short  s16x8;
typedef __attribute__((ext_vector_type(4))) int    i32x4;

#define MFMA32(a,b,c) __builtin_amdgcn_mfma_f32_16x16x32_bf16((a),(b),(c),0,0,0)

__device__ __forceinline__ short f2bf(float f) {
  unsigned u = __float_as_uint(f);
  u = (u + 0x7fffu + ((u >> 16) & 1u)) >> 16;
  return (short)u;
}
__device__ __forceinline__ unsigned packbf(float lo, float hi) {
  return (unsigned)(u16)f2bf(lo) | ((unsigned)(u16)f2bf(hi) << 16);
}
__device__ __forceinline__ unsigned cvtpk(float a, float b) {
  float2 f; f.x = a; f.y = b;
  __hip_bfloat162 h = __float22bfloat162_rn(f);
  unsigned u; __builtin_memcpy(&u, &h, 4); return u;
}

// Geometry: B=16,T=4096,C=256 -> 256 windows of W=256, H=4, DH=64, RADIUS=32

// ---------------- K0: weight cast + transpose ----------------
__global__ __launch_bounds__(256) void k_prep(const float* __restrict__ wqkv,
                                              const float* __restrict__ wproj,
                                              u16* __restrict__ wqkvT,
                                              u16* __restrict__ wprojT) {
  int idx = blockIdx.x * 256 + threadIdx.x;
  if (idx < 768 * 256) {
    int n = idx >> 8, kk = idx & 255;
    wqkvT[idx] = (u16)f2bf(wqkv[kk * 768 + n]);
  } else {
    int j = idx - 768 * 256;
    int n = j >> 8, kk = j & 255;
    wprojT[j] = (u16)f2bf(wproj[kk * 256 + n]);
  }
}

// ---------------- K1: fully fused per-window QKV + banded attention + projection ----
// 1 block = 1 window (256 rows). 8 waves; wave w owns output rows 32w..32w+31.
// LDS bytes: K [j256][d64] @0 (32KB) | V^T [d64][j256] @32768 | Q [q256][d64] @65536
//            | Otmp per-wave 32x64 @98304 + w*4096.  All XOR-swizzled ^((row&7)<<4).
// __launch_bounds__(512, 2): LDS already caps at 1 block/CU (= 2 waves/EU), so this
// is free occupancy-wise and raises the VGPR budget to 256 -> xa/of stay in registers
// (round-14's 128-reg budget spilled them: +40MB FETCH / +60MB WRITE of scratch).
__global__ __launch_bounds__(512, 2) void k_fused(const float* __restrict__ x,
                                                  const u16* __restrict__ wqkvT,
                                                  const u16* __restrict__ wprojT,
                                                  const float* __restrict__ bias,
                                                  float* __restrict__ out) {
  __shared__ u16 lds[65536];           // 128 KiB
  char* ldsb = (char*)lds;
  const int tid = threadIdx.x;
  const int lane = tid & 63, w = tid >> 6;
  const int c15 = lane & 15, g = lane >> 4;
  const int win = blockIdx.x;
  const unsigned swzq = ((unsigned)(c15 & 7)) << 4;   // swizzle for rows ≡ c15 (mod 8)

  // ---- x rows -> A-fragments in registers (reused 12x: Q,K GEMMs as A; V^T as B) ----
  s16x8 xa[2][8];
#pragma unroll
  for (int mt = 0; mt < 2; ++mt) {
    const float* xp = x + ((size_t)win * 256 + w * 32 + mt * 16 + c15) * 256;
#pragma unroll
    for (int kc = 0; kc < 8; ++kc) {
      f32x4 a = *(const f32x4*)(xp + kc * 32 + g * 8);
      f32x4 b = *(const f32x4*)(xp + kc * 32 + g * 8 + 4);
      i32x4 t = { (int)cvtpk(a[0], a[1]), (int)cvtpk(a[2], a[3]),
                  (int)cvtpk(b[0], b[1]), (int)cvtpk(b[2], b[3]) };
      xa[mt][kc] = *(s16x8*)&t;
    }
  }

  s16x8 of[2][8];    // O as projection A-frags (head h fills kc = 2h, 2h+1)

#pragma unroll
  for (int h = 0; h < 4; ++h) {
    // ---- GEMM Q (which=0 -> LDS @65536) and K (which=1 -> LDS @0) ----
#pragma unroll
    for (int wq = 0; wq < 2; ++wq) {
      const u16* wb = wqkvT + (size_t)(wq * 256 + h * 64) * 256;
      f32x4 acc[2][4] = {};
#pragma unroll
      for (int kc = 0; kc < 8; ++kc) {
        s16x8 bf[4];
#pragma unroll
        for (int nt = 0; nt < 4; ++nt)
          bf[nt] = *(const s16x8*)(wb + (size_t)(nt * 16 + c15) * 256 + kc * 32 + g * 8);
#pragma unroll
        for (int mt = 0; mt < 2; ++mt)
#pragma unroll
          for (int nt = 0; nt < 4; ++nt)
            acc[mt][nt] = MFMA32(xa[mt][kc], bf[nt], acc[mt][nt]);
      }
      char* dst = ldsb + (wq ? 0 : 65536);
#pragma unroll
      for (int mt = 0; mt < 2; ++mt)
#pragma unroll
        for (int nt = 0; nt < 4; ++nt)
#pragma unroll
          for (int r = 0; r < 4; ++r) {
            int row = w * 32 + mt * 16 + g * 4 + r;
            unsigned b = (unsigned)(row * 128 + (nt * 16 + c15) * 2) ^ (((unsigned)(row & 7)) << 4);
            *(u16*)(dst + b) = (u16)f2bf(acc[mt][nt][r]);
          }
    }
    // ---- GEMM V^T (which=2): A = W_V rows (d), B = xa (x as B-frag) -> LDS @32768 ----
    {
      const u16* wv = wqkvT + (size_t)(512 + h * 64) * 256;
      f32x4 acc[4][2] = {};
#pragma unroll
      for (int kc = 0; kc < 8; ++kc) {
        s16x8 af[4];
#pragma unroll
        for (int mtv = 0; mtv < 4; ++mtv)
          af[mtv] = *(const s16x8*)(wv + (size_t)(mtv * 16 + c15) * 256 + kc * 32 + g * 8);
#pragma unroll
        for (int mtv = 0; mtv < 4; ++mtv)
#pragma unroll
          for (int ntx = 0; ntx < 2; ++ntx)
            acc[mtv][ntx] = MFMA32(af[mtv], xa[ntx][kc], acc[mtv][ntx]);
      }
#pragma unroll
      for (int mtv = 0; mtv < 4; ++mtv)
#pragma unroll
        for (int ntx = 0; ntx < 2; ++ntx)
#pragma unroll
          for (int r = 0; r < 4; ++r) {
            int d = mtv * 16 + g * 4 + r;
            int j = w * 32 + ntx * 16 + c15;
            unsigned b = (unsigned)(d * 512 + j * 2) ^ (((unsigned)(d & 7)) << 4);
            *(u16*)(ldsb + 32768 + b) = (u16)f2bf(acc[mtv][ntx][r]);
          }
    }
    __syncthreads();   // K/V^T/Q published

    // ---- banded attention for this head, 2 q-tiles per wave ----
#pragma unroll
    for (int ii = 0; ii < 2; ++ii) {
      const int i16 = w * 2 + ii;
      const int qrow = i16 * 16 + c15;
      const s16x8 qf0 = *(const s16x8*)(ldsb + 65536 + ((unsigned)(qrow * 128 + g * 16) ^ swzq));
      const s16x8 qf1 = *(const s16x8*)(ldsb + 65536 + ((unsigned)(qrow * 128 + 64 + g * 16) ^ swzq));
      s16x8 kl0, kh0, kl1 = {}, kh1 = {}, kl2 = {}, kh2 = {};
      {
        int row = i16 * 16 + c15;
        kl0 = *(const s16x8*)(ldsb + ((unsigned)(row * 128 + g * 16) ^ swzq));
        kh0 = *(const s16x8*)(ldsb + ((unsigned)(row * 128 + 64 + g * 16) ^ swzq));
      }
      if (i16 >= 1) {
        int row = (i16 - 1) * 16 + c15;
        kl1 = *(const s16x8*)(ldsb + ((unsigned)(row * 128 + g * 16) ^ swzq));
        kh1 = *(const s16x8*)(ldsb + ((unsigned)(row * 128 + 64 + g * 16) ^ swzq));
      }
      if (i16 >= 2) {
        int row = (i16 - 2) * 16 + c15;
        kl2 = *(const s16x8*)(ldsb + ((unsigned)(row * 128 + g * 16) ^ swzq));
        kh2 = *(const s16x8*)(ldsb + ((unsigned)(row * 128 + 64 + g * 16) ^ swzq));
      }

      f32x4 sT0 = {}, sT1 = {}, sT2 = {};
      sT0 = MFMA32(kl0, qf0, sT0); sT0 = MFMA32(kh0, qf1, sT0);
      if (i16 >= 1) { sT1 = MFMA32(kl1, qf0, sT1); sT1 = MFMA32(kh1, qf1, sT1); }
      if (i16 >= 2) { sT2 = MFMA32(kl2, qf0, sT2); sT2 = MFMA32(kh2, qf1, sT2); }

      float e0[4], e1[4], e2[4];
      float vmax = -3.0e38f;
#pragma unroll
      for (int r = 0; r < 4; ++r) {
        int dd = qrow - (i16 * 16 + g * 4 + r);
        e0[r] = (dd >= 0 && dd <= 32) ? sT0[r] * 0.125f : -1.0e30f;
        vmax = fmaxf(vmax, e0[r]);
      }
      if (i16 >= 1) {
#pragma unroll
        for (int r = 0; r < 4; ++r) {          // dd in 1..31, always in band
          e1[r] = sT1[r] * 0.125f;
          vmax = fmaxf(vmax, e1[r]);
        }
      }
      if (i16 >= 2) {
#pragma unroll
        for (int r = 0; r < 4; ++r) {
          int dd = qrow - ((i16 - 2) * 16 + g * 4 + r);   // 17..47
          e2[r] = (dd <= 32) ? sT2[r] * 0.125f : -1.0e30f;
          vmax = fmaxf(vmax, e2[r]);
        }
      }
      vmax = fmaxf(vmax, __shfl_xor(vmax, 16));
      vmax = fmaxf(vmax, __shfl_xor(vmax, 32));
      float ssum = 0.0f;
#pragma unroll
      for (int r = 0; r < 4; ++r) { e0[r] = __expf(e0[r] - vmax); ssum += e0[r]; }
      if (i16 >= 1) {
#pragma unroll
        for (int r = 0; r < 4; ++r) { e1[r] = __expf(e1[r] - vmax); ssum += e1[r]; }
      }
      if (i16 >= 2) {
#pragma unroll
        for (int r = 0; r < 4; ++r) { e2[r] = __expf(e2[r] - vmax); ssum += e2[r]; }
      }
      ssum += __shfl_xor(ssum, 16);
      ssum += __shfl_xor(ssum, 32);
      const float inv = 1.0f / ssum;

      unsigned c0a = packbf(e0[0] * inv, e0[1] * inv), c0b = packbf(e0[2] * inv, e0[3] * inv);
      unsigned c1a = 0, c1b = 0, c2a = 0, c2b = 0;
      if (i16 >= 1) { c1a = packbf(e1[0] * inv, e1[1] * inv); c1b = packbf(e1[2] * inv, e1[3] * inv); }
      if (i16 >= 2) { c2a = packbf(e2[0] * inv, e2[1] * inv); c2b = packbf(e2[2] * inv, e2[3] * inv); }

      const int src0 = ((g & 1) << 5) + c15;
      const int src1 = src0 + 16;
      const bool alo = (g < 2);
#define MKFRAG(pa, ua, ub) do {                                             \
        int _t0 = __shfl((int)(ua), src0), _t1 = __shfl((int)(ub), src0);   \
        int _t2 = __shfl((int)(ua), src1), _t3 = __shfl((int)(ub), src1);   \
        i32x4 _ti = { alo ? _t0 : 0, alo ? _t1 : 0, alo ? _t2 : 0, alo ? _t3 : 0 }; \
        pa = *(s16x8*)&_ti;                                                 \
      } while (0)
      s16x8 pa0, pa1, pa2;
      MKFRAG(pa0, c0a, c0b);
      MKFRAG(pa1, c1a, c1b);
      MKFRAG(pa2, c2a, c2b);
#undef MKFRAG

      f32x4 oa[4] = {};
#pragma unroll
      for (int dt = 0; dt < 4; ++dt) {
        int d = dt * 16 + c15;
        s16x8 v0 = *(const s16x8*)(ldsb + 32768 +
                    ((unsigned)(d * 512 + (i16 * 16 + (g & 1) * 8) * 2) ^ swzq));
        oa[dt] = MFMA32(pa0, v0, oa[dt]);
        if (i16 >= 1) {
          s16x8 v1 = *(const s16x8*)(ldsb + 32768 +
                      ((unsigned)(d * 512 + ((i16 - 1) * 16 + (g & 1) * 8) * 2) ^ swzq));
          oa[dt] = MFMA32(pa1, v1, oa[dt]);
        }
        if (i16 >= 2) {
          s16x8 v2 = *(const s16x8*)(ldsb + 32768 +
                      ((unsigned)(d * 512 + ((i16 - 2) * 16 + (g & 1) * 8) * 2) ^ swzq));
          oa[dt] = MFMA32(pa2, v2, oa[dt]);
        }
      }
      // O tile -> per-wave Otmp
#pragma unroll
      for (int dt = 0; dt < 4; ++dt)
#pragma unroll
        for (int r = 0; r < 4; ++r) {
          int lrow = ii * 16 + g * 4 + r;
          unsigned b = (unsigned)(lrow * 128 + (dt * 16 + c15) * 2) ^ (((unsigned)(lrow & 7)) << 4);
          *(u16*)(ldsb + 98304 + w * 4096 + b) = (u16)f2bf(oa[dt][r]);
        }
    } // ii

    // ---- O readback as projection A-frags (own-wave region; cols h*64..h*64+63) ----
#pragma unroll
    for (int mt = 0; mt < 2; ++mt)
#pragma unroll
      for (int kh = 0; kh < 2; ++kh) {
        unsigned b = (unsigned)((mt * 16 + c15) * 128 + kh * 64 + g * 16) ^ swzq;
        of[mt][h * 2 + kh] = *(const s16x8*)(ldsb + 98304 + w * 4096 + b);
      }
    __syncthreads();   // protect K/V/Q LDS reuse by next head
  } // h

  // ---- projection: out = O @ Wproj + bias (per wave: 32 rows x 256 cols) ----
  const int obase = win * 256 + w * 32;
  for (int nt = 0; nt < 16; ++nt) {
    s16x8 bp[8];
#pragma unroll
    for (int kc = 0; kc < 8; ++kc)
      bp[kc] = *(const s16x8*)(wprojT + (size_t)(nt * 16 + c15) * 256 + kc * 32 + g * 8);
    const float bv = bias[nt * 16 + c15];
    f32x4 a0 = {bv, bv, bv, bv};
    f32x4 a1 = {bv, bv, bv, bv};
#pragma unroll
    for (int kc = 0; kc < 8; ++kc) {
      a0 = MFMA32(of[0][kc], bp[kc], a0);
      a1 = MFMA32(of[1][kc], bp[kc], a1);
    }
#pragma unroll
    for (int r = 0; r < 4; ++r) {
      out[(size_t)(obase + g * 4 + r) * 256 + nt * 16 + c15] = a0[r];
      out[(size_t)(obase + 16 + g * 4 + r) * 256 + nt * 16 + c15] = a1[r];
    }
  }
}

extern "C" void kernel_launch(void* const* d_in, const int* in_sizes, int n_in,
                              void* d_out, int out_size, void* d_ws, size_t ws_size,
                              hipStream_t stream) {
  (void)in_sizes; (void)n_in; (void)out_size;
  const float* x     = (const float*)d_in[0];
  const float* wqkv  = (const float*)d_in[1];
  const float* wproj = (const float*)d_in[2];
  const float* bias  = (const float*)d_in[3];
  float* out = (float*)d_out;
  char* ws = (char*)d_ws;

  const size_t wBytes = (size_t)768 * 256 * 2 + (size_t)256 * 256 * 2;  // 524288
  if (ws_size < wBytes) return;
  u16* wqkvT  = (u16*)ws;
  u16* wprojT = (u16*)(ws + (size_t)768 * 256 * 2);

  k_prep<<<1024, 256, 0, stream>>>(wqkv, wproj, wqkvT, wprojT);
  k_fused<<<256, 512, 0, stream>>>(x, wqkvT, wprojT, bias, out);
}